// Round 2
// baseline (721.766 us; speedup 1.0000x reference)
//
#include <hip/hip_runtime.h>

#define NUM_GENES 20000
#define NUM_FEAT  256
#define BATCH     32
#define VOCAB     9
#define BLOCKS_PER_B 625   // 20000 / 32 rows per block

// Single-block kernel: zero the per-gene flag array, then scatter the
// masked geneset. Races on flag writes are benign (all write 1).
__global__ void build_flags_kernel(const int* __restrict__ geneset,
                                   int n_mask,
                                   int* __restrict__ flags) {
    for (int i = threadIdx.x; i < NUM_GENES; i += blockDim.x) flags[i] = 0;
    __syncthreads();
    for (int i = threadIdx.x; i < n_mask; i += blockDim.x) {
        int g = geneset[i];
        if (g >= 0 && g < NUM_GENES) flags[g] = 1;
    }
}

// out[b,g,f] = gene_table[g,f] + mut_table[flags[g] ? 8 : X[b,g], f]
// float32 everywhere. One block = 32 consecutive gene rows of one batch
// element (32 rows * 1024 B = 32 KB contiguous output).
// Row = 256 floats = 64 float4 vectors; 64 lanes (one wave) per row, so
// flags[g]/X[b,g] loads are wave-uniform (broadcast, zero divergence).
__global__ __launch_bounds__(256) void add_emb_kernel(
        const float* __restrict__ gene_table,  // [G,256] f32
        const float* __restrict__ mut_table,   // [9,256] f32
        const int*   __restrict__ X,           // [B,G]
        const int*   __restrict__ flags,       // [G]
        float*       __restrict__ out)         // [B,G,256] f32
{
    const int bb    = blockIdx.x;
    const int b     = bb / BLOCKS_PER_B;
    const int gbase = (bb - b * BLOCKS_PER_B) * 32;
    const int t     = threadIdx.x;
    const int fvec  = t & 63;   // which 16B float4 within the 256-feat row
    const int rsub  = t >> 6;   // 0..3: row within the 4-row group

    const float4* gt = (const float4*)gene_table;  // 64 vec per row
    const float4* mt = (const float4*)mut_table;
    float4*       o  = (float4*)out;

#pragma unroll
    for (int i = 0; i < 8; ++i) {
        const int g   = gbase + i * 4 + rsub;
        const int tok = flags[g] ? (VOCAB - 1) : X[b * NUM_GENES + g];

        const float4 a = gt[(size_t)g * 64 + fvec];
        const float4 m = mt[(size_t)tok * 64 + fvec];

        float4 r;
        r.x = a.x + m.x;
        r.y = a.y + m.y;
        r.z = a.z + m.z;
        r.w = a.w + m.w;

        o[((size_t)b * NUM_GENES + g) * 64 + fvec] = r;
    }
}

extern "C" void kernel_launch(void* const* d_in, const int* in_sizes, int n_in,
                              void* d_out, int out_size, void* d_ws, size_t ws_size,
                              hipStream_t stream) {
    // setup_inputs() order:
    // 0: X_converted   [32,20000] int32
    // 1: mask_percentage (scalar, unused — test_geneset branch)
    // 2: test_geneset  [2000] int32
    // 3: gene_table    [20000,256] float32
    // 4: mut_table     [9,256]     float32
    const int*   X          = (const int*)d_in[0];
    const int*   geneset    = (const int*)d_in[2];
    const float* gene_table = (const float*)d_in[3];
    const float* mut_table  = (const float*)d_in[4];
    const int    n_mask     = in_sizes[2];

    int*   flags = (int*)d_ws;   // 20000 * 4 B = 80 KB scratch
    float* out   = (float*)d_out;

    build_flags_kernel<<<1, 1024, 0, stream>>>(geneset, n_mask, flags);
    add_emb_kernel<<<BATCH * BLOCKS_PER_B, 256, 0, stream>>>(
        gene_table, mut_table, X, flags, out);
}